// Round 8
// baseline (240.889 us; speedup 1.0000x reference)
//
#include <hip/hip_runtime.h>

#define BROWS 8192
#define TLEN  1024
#define GRID  (BROWS / 4)   // 2048 blocks, 4 rows (waves) per block

typedef float f32x4 __attribute__((ext_vector_type(4)));
typedef int   i32x4 __attribute__((ext_vector_type(4)));

// d_ws layout: [0..4) float sum_acc | [4..8) float cnt_acc | [8..12) int arrive
// (zeroed by a 16 B hipMemsetAsync before launch)

// One wave per row; 4 rows per 256-thread block; grid = 2048. Round 7's body
// (nt loads, branchless, wave-local reduce) + fused finalize: one LDS block
// reduce, one f32 atomicAdd pair per block, last-arriving block writes out.
__global__ __launch_bounds__(256) void row_reduce_kernel(
    const int*   __restrict__ seq,
    const float* __restrict__ logp,
    const float* __restrict__ value,
    const float* __restrict__ reward,
    float*       __restrict__ sum_acc,
    float*       __restrict__ cnt_acc,
    int*         __restrict__ arrive,
    float*       __restrict__ out)
{
    const int wave = threadIdx.x >> 6;
    const int lane = threadIdx.x & 63;
    const int row  = blockIdx.x * 4 + wave;

    const size_t rowoff = (size_t)row * TLEN;
    const i32x4* s4 = (const i32x4*)(seq    + rowoff);
    const f32x4* l4 = (const f32x4*)(logp   + rowoff);
    const f32x4* v4 = (const f32x4*)(value  + rowoff);
    const f32x4* r4 = (const f32x4*)(reward + rowoff);

    i32x4 s[4];
    f32x4 l[4], v[4], r[4];
    #pragma unroll
    for (int k = 0; k < 4; ++k) {
        const int idx = k * 64 + lane;          // coalesced 1KB/wave per load
        s[k] = __builtin_nontemporal_load(s4 + idx);
        l[k] = __builtin_nontemporal_load(l4 + idx);
        v[k] = __builtin_nontemporal_load(v4 + idx);
        r[k] = __builtin_nontemporal_load(r4 + idx);
    }

    // Per-lane first-zero among its 16 tokens (absolute index; TLEN = none).
    int lfz = TLEN;
    #pragma unroll
    for (int k = 3; k >= 0; --k) {
        const int base = k * 256 + lane * 4;
        if (s[k][3] == 0) lfz = base + 3;
        if (s[k][2] == 0) lfz = base + 2;
        if (s[k][1] == 0) lfz = base + 1;
        if (s[k][0] == 0) lfz = base + 0;
    }

    // Wave min butterfly -> row first-zero.
    int fz = lfz;
    #pragma unroll
    for (int off = 32; off > 0; off >>= 1)
        fz = min(fz, __shfl_xor(fz, off, 64));

    // Branchless masked products; mask[t] = 1 iff t <= fz (absmax 0.0 r1-r7).
    float a0 = 0.0f, a1 = 0.0f, a2 = 0.0f, a3 = 0.0f;
    #pragma unroll
    for (int k = 0; k < 4; ++k) {
        const int base = k * 256 + lane * 4;
        a0 += (base + 0 <= fz) ? (-l[k][0] * (r[k][0] - v[k][0])) : 0.0f;
        a1 += (base + 1 <= fz) ? (-l[k][1] * (r[k][1] - v[k][1])) : 0.0f;
        a2 += (base + 2 <= fz) ? (-l[k][2] * (r[k][2] - v[k][2])) : 0.0f;
        a3 += (base + 3 <= fz) ? (-l[k][3] * (r[k][3] - v[k][3])) : 0.0f;
    }
    float acc = (a0 + a1) + (a2 + a3);

    // Wave f32 butterfly sum.
    #pragma unroll
    for (int off = 32; off > 0; off >>= 1)
        acc += __shfl_xor(acc, off, 64);

    // Block reduce (4 waves) through LDS, then one atomic pair per block.
    __shared__ float ls[4], lc[4];
    if (lane == 0) {
        ls[wave] = acc;
        lc[wave] = (float)min(fz + 1, TLEN);    // integer-valued, exact in f32
    }
    __syncthreads();

    if (threadIdx.x == 0) {
        const float bs = (ls[0] + ls[1]) + (ls[2] + ls[3]);
        const float bc = (lc[0] + lc[1]) + (lc[2] + lc[3]);
        atomicAdd(sum_acc, bs);
        atomicAdd(cnt_acc, bc);
        __threadfence();                        // adds visible before arrive
        const int old = atomicAdd(arrive, 1);
        if (old == GRID - 1) {
            const float ts = atomicAdd(sum_acc, 0.0f);  // coherent reads
            const float tc = atomicAdd(cnt_acc, 0.0f);
            out[0] = ts / tc;
        }
    }
}

extern "C" void kernel_launch(void* const* d_in, const int* in_sizes, int n_in,
                              void* d_out, int out_size, void* d_ws, size_t ws_size,
                              hipStream_t stream) {
    const int*   seq    = (const int*)  d_in[0];
    const float* logp   = (const float*)d_in[1];
    const float* value  = (const float*)d_in[2];
    const float* reward = (const float*)d_in[3];
    float* out = (float*)d_out;

    float* sum_acc = (float*)d_ws;
    float* cnt_acc = sum_acc + 1;
    int*   arrive  = (int*)((char*)d_ws + 8);

    hipMemsetAsync(d_ws, 0, 16, stream);        // zero accumulators (graph-legal)
    row_reduce_kernel<<<GRID, 256, 0, stream>>>(seq, logp, value, reward,
                                                sum_acc, cnt_acc, arrive, out);
}

// Round 9
// 151.246 us; speedup vs baseline: 1.5927x; 1.5927x over previous
//
#include <hip/hip_runtime.h>

#define BROWS 8192
#define TLEN  1024
#define GRID  (BROWS / 8)   // 1024 blocks; 4 waves/block; 2 rows per wave

typedef float f32x4 __attribute__((ext_vector_type(4)));
typedef int   i32x4 __attribute__((ext_vector_type(4)));

// Round 7's winning structure (nt loads, branchless, wave-local reduce, no
// barriers, separate final kernel — NO device fences/atomics) with ONE change:
// each wave handles 2 rows, all 32 nontemporal loads issued up-front to
// double memory-level parallelism per wave.
__global__ __launch_bounds__(256) void row_reduce_kernel(
    const int*   __restrict__ seq,
    const float* __restrict__ logp,
    const float* __restrict__ value,
    const float* __restrict__ reward,
    float*       __restrict__ row_sum,
    float*       __restrict__ row_cnt)
{
    const int wave = threadIdx.x >> 6;
    const int lane = threadIdx.x & 63;
    const int row0 = blockIdx.x * 8 + wave * 2;   // this wave's two rows

    i32x4 s[2][4];
    f32x4 l[2][4], v[2][4], r[2][4];

    // Issue ALL 32 loads up-front (2 rows x 4 arrays x 4 vec4).
    #pragma unroll
    for (int j = 0; j < 2; ++j) {
        const size_t rowoff = (size_t)(row0 + j) * TLEN;
        const i32x4* s4 = (const i32x4*)(seq    + rowoff);
        const f32x4* l4 = (const f32x4*)(logp   + rowoff);
        const f32x4* v4 = (const f32x4*)(value  + rowoff);
        const f32x4* r4 = (const f32x4*)(reward + rowoff);
        #pragma unroll
        for (int k = 0; k < 4; ++k) {
            const int idx = k * 64 + lane;        // coalesced 1KB/wave per load
            s[j][k] = __builtin_nontemporal_load(s4 + idx);
            l[j][k] = __builtin_nontemporal_load(l4 + idx);
            v[j][k] = __builtin_nontemporal_load(v4 + idx);
            r[j][k] = __builtin_nontemporal_load(r4 + idx);
        }
    }

    #pragma unroll
    for (int j = 0; j < 2; ++j) {
        // Per-lane first-zero among its 16 tokens (absolute; TLEN = none).
        int lfz = TLEN;
        #pragma unroll
        for (int k = 3; k >= 0; --k) {
            const int base = k * 256 + lane * 4;
            if (s[j][k][3] == 0) lfz = base + 3;
            if (s[j][k][2] == 0) lfz = base + 2;
            if (s[j][k][1] == 0) lfz = base + 1;
            if (s[j][k][0] == 0) lfz = base + 0;
        }

        // Wave min butterfly -> row first-zero.
        int fz = lfz;
        #pragma unroll
        for (int off = 32; off > 0; off >>= 1)
            fz = min(fz, __shfl_xor(fz, off, 64));

        // Branchless masked products; mask[t]=1 iff t<=fz (absmax 0.0 r1-r8).
        float a0 = 0.0f, a1 = 0.0f, a2 = 0.0f, a3 = 0.0f;
        #pragma unroll
        for (int k = 0; k < 4; ++k) {
            const int base = k * 256 + lane * 4;
            a0 += (base + 0 <= fz) ? (-l[j][k][0] * (r[j][k][0] - v[j][k][0])) : 0.0f;
            a1 += (base + 1 <= fz) ? (-l[j][k][1] * (r[j][k][1] - v[j][k][1])) : 0.0f;
            a2 += (base + 2 <= fz) ? (-l[j][k][2] * (r[j][k][2] - v[j][k][2])) : 0.0f;
            a3 += (base + 3 <= fz) ? (-l[j][k][3] * (r[j][k][3] - v[j][k][3])) : 0.0f;
        }
        float acc = (a0 + a1) + (a2 + a3);

        // Wave f32 butterfly sum.
        #pragma unroll
        for (int off = 32; off > 0; off >>= 1)
            acc += __shfl_xor(acc, off, 64);

        if (lane == 0) {
            row_sum[row0 + j] = acc;
            row_cnt[row0 + j] = (float)min(fz + 1, TLEN);
        }
    }
}

// Single block: deterministic f64 reduce of 8192 row partials -> scalar.
__global__ __launch_bounds__(256) void final_reduce_kernel(
    const float* __restrict__ row_sum,
    const float* __restrict__ row_cnt,
    float*       __restrict__ out)
{
    const int tid  = threadIdx.x;
    const int lane = tid & 63;
    const int wave = tid >> 6;

    double s = 0.0, c = 0.0;
    for (int i = tid; i < BROWS; i += 256) {
        s += (double)row_sum[i];
        c += (double)row_cnt[i];
    }
    #pragma unroll
    for (int off = 32; off > 0; off >>= 1) {
        s += __shfl_xor(s, off, 64);
        c += __shfl_xor(c, off, 64);
    }
    __shared__ double ls[4], lc[4];
    if (lane == 0) { ls[wave] = s; lc[wave] = c; }
    __syncthreads();
    if (tid == 0) {
        double ts = (ls[0] + ls[1]) + (ls[2] + ls[3]);
        double tc = (lc[0] + lc[1]) + (lc[2] + lc[3]);
        out[0] = (float)(ts / tc);
    }
}

extern "C" void kernel_launch(void* const* d_in, const int* in_sizes, int n_in,
                              void* d_out, int out_size, void* d_ws, size_t ws_size,
                              hipStream_t stream) {
    const int*   seq    = (const int*)  d_in[0];
    const float* logp   = (const float*)d_in[1];
    const float* value  = (const float*)d_in[2];
    const float* reward = (const float*)d_in[3];
    float* out = (float*)d_out;

    float* row_sum = (float*)d_ws;            // 8192 * 4 B
    float* row_cnt = row_sum + BROWS;         // 8192 * 4 B

    row_reduce_kernel<<<GRID, 256, 0, stream>>>(seq, logp, value, reward,
                                                row_sum, row_cnt);
    final_reduce_kernel<<<1, 256, 0, stream>>>(row_sum, row_cnt, out);
}

// Round 10
// 147.733 us; speedup vs baseline: 1.6306x; 1.0238x over previous
//
#include <hip/hip_runtime.h>

#define BROWS 8192
#define TLEN  1024

typedef float f32x4 __attribute__((ext_vector_type(4)));
typedef int   i32x4 __attribute__((ext_vector_type(4)));

// BEST-MEASURED STRUCTURE (round 7, 147.6 us): one wave per row, 4 rows per
// 256-thread block, grid = 2048. 16 nontemporal loads per lane issued
// up-front (nt = the only measured win: skips L1/L2 allocation on read-once
// streams, 156->149 us). Zero LDS, zero barriers, f32 math, branchless.
// seq loads issued FIRST so the fz chain starts while l/v/r are in flight.
//
// Falsified levers (do not revisit): persistence/atomics (-41%), per-block
// __threadfence on 8-XCD parts (-60%), f64 hot-path accumulate, 32-deep MLP,
// fused finalize, split-phase streaming.
__global__ __launch_bounds__(256) void row_reduce_kernel(
    const int*   __restrict__ seq,
    const float* __restrict__ logp,
    const float* __restrict__ value,
    const float* __restrict__ reward,
    float*       __restrict__ row_sum,
    float*       __restrict__ row_cnt)
{
    const int row  = blockIdx.x * 4 + (threadIdx.x >> 6);
    const int lane = threadIdx.x & 63;

    const size_t rowoff = (size_t)row * TLEN;
    const i32x4* s4 = (const i32x4*)(seq    + rowoff);
    const f32x4* l4 = (const f32x4*)(logp   + rowoff);
    const f32x4* v4 = (const f32x4*)(value  + rowoff);
    const f32x4* r4 = (const f32x4*)(reward + rowoff);

    i32x4 s[4];
    f32x4 l[4], v[4], r[4];
    // seq first: fz depends only on s.
    #pragma unroll
    for (int k = 0; k < 4; ++k)
        s[k] = __builtin_nontemporal_load(s4 + (k * 64 + lane));
    #pragma unroll
    for (int k = 0; k < 4; ++k) {
        const int idx = k * 64 + lane;          // coalesced 1KB/wave per load
        l[k] = __builtin_nontemporal_load(l4 + idx);
        v[k] = __builtin_nontemporal_load(v4 + idx);
        r[k] = __builtin_nontemporal_load(r4 + idx);
    }

    // Per-lane first-zero among its 16 tokens (absolute index; TLEN = none).
    // Descending overwrite -> smallest index wins.
    int lfz = TLEN;
    #pragma unroll
    for (int k = 3; k >= 0; --k) {
        const int base = k * 256 + lane * 4;
        if (s[k][3] == 0) lfz = base + 3;
        if (s[k][2] == 0) lfz = base + 2;
        if (s[k][1] == 0) lfz = base + 1;
        if (s[k][0] == 0) lfz = base + 0;
    }

    // Wave min butterfly -> row first-zero.
    int fz = lfz;
    #pragma unroll
    for (int off = 32; off > 0; off >>= 1)
        fz = min(fz, __shfl_xor(fz, off, 64));

    // Branchless masked products, 4 independent f32 chains per lane.
    // mask[t] = 1 iff t <= fz (verified absmax 0.0 across rounds 1-9).
    float a0 = 0.0f, a1 = 0.0f, a2 = 0.0f, a3 = 0.0f;
    #pragma unroll
    for (int k = 0; k < 4; ++k) {
        const int base = k * 256 + lane * 4;
        a0 += (base + 0 <= fz) ? (-l[k][0] * (r[k][0] - v[k][0])) : 0.0f;
        a1 += (base + 1 <= fz) ? (-l[k][1] * (r[k][1] - v[k][1])) : 0.0f;
        a2 += (base + 2 <= fz) ? (-l[k][2] * (r[k][2] - v[k][2])) : 0.0f;
        a3 += (base + 3 <= fz) ? (-l[k][3] * (r[k][3] - v[k][3])) : 0.0f;
    }
    float acc = (a0 + a1) + (a2 + a3);

    // Wave f32 butterfly sum.
    #pragma unroll
    for (int off = 32; off > 0; off >>= 1)
        acc += __shfl_xor(acc, off, 64);

    if (lane == 0) {
        row_sum[row] = acc;
        row_cnt[row] = (float)min(fz + 1, TLEN);
    }
}

// Single block: deterministic f64 reduce of 8192 row partials -> scalar.
__global__ __launch_bounds__(256) void final_reduce_kernel(
    const float* __restrict__ row_sum,
    const float* __restrict__ row_cnt,
    float*       __restrict__ out)
{
    const int tid  = threadIdx.x;
    const int lane = tid & 63;
    const int wave = tid >> 6;

    double s = 0.0, c = 0.0;
    for (int i = tid; i < BROWS; i += 256) {
        s += (double)row_sum[i];
        c += (double)row_cnt[i];
    }
    #pragma unroll
    for (int off = 32; off > 0; off >>= 1) {
        s += __shfl_xor(s, off, 64);
        c += __shfl_xor(c, off, 64);
    }
    __shared__ double ls[4], lc[4];
    if (lane == 0) { ls[wave] = s; lc[wave] = c; }
    __syncthreads();
    if (tid == 0) {
        double ts = (ls[0] + ls[1]) + (ls[2] + ls[3]);
        double tc = (lc[0] + lc[1]) + (lc[2] + lc[3]);
        out[0] = (float)(ts / tc);
    }
}

extern "C" void kernel_launch(void* const* d_in, const int* in_sizes, int n_in,
                              void* d_out, int out_size, void* d_ws, size_t ws_size,
                              hipStream_t stream) {
    const int*   seq    = (const int*)  d_in[0];
    const float* logp   = (const float*)d_in[1];
    const float* value  = (const float*)d_in[2];
    const float* reward = (const float*)d_in[3];
    float* out = (float*)d_out;

    float* row_sum = (float*)d_ws;            // 8192 * 4 B
    float* row_cnt = row_sum + BROWS;         // 8192 * 4 B

    row_reduce_kernel<<<BROWS / 4, 256, 0, stream>>>(seq, logp, value, reward,
                                                     row_sum, row_cnt);
    final_reduce_kernel<<<1, 256, 0, stream>>>(row_sum, row_cnt, out);
}